// Round 13
// baseline (369.393 us; speedup 1.0000x reference)
//
#include <hip/hip_runtime.h>

#define NSHOTS 4
#define NT     512
#define NZ     256
#define NX     256
#define NRECS  128

static constexpr float DTf    = 0.001f;
static constexpr float INVDH2 = 1.0f / (10.0f * 10.0f);

#define KS     8                  // fused steps per phase (= halo radius)
#define TZI    8                  // interior z rows per tile
#define TXI    48                 // interior x cols per tile
#define EXTZ   24                 // ext z rows = TZI + 2*KS
#define NW     6                  // waves per WG (EXTZ/RPW)
#define RPW    4                  // ext rows per wave
#define NPAIRS 2                  // v2f row-pairs per thread
#define BLOCK  384                // 6 waves
#define NTZ    32                 // z tiles (256/8)
#define NTX    6                  // x tiles (48-wide, last ragged)
#define NTILES (NSHOTS*NTZ*NTX)   // 768 WGs -> 3 per CU (co-resident)
#define NPH    (NT/KS)            // 64

typedef float v2f __attribute__((ext_vector_type(2)));
typedef unsigned long long ull;

// lane i <- lane i-1 (left x-neighbor); OOB lane 0 reads 0 (bound_ctrl=1)
__device__ __forceinline__ float nbr_left(float v) {
  return __int_as_float(__builtin_amdgcn_update_dpp(
      0, __float_as_int(v), 0x138 /*WAVE_SHR1*/, 0xf, 0xf, true));
}
// lane i <- lane i+1 (right x-neighbor); OOB lane 63 reads 0
__device__ __forceinline__ float nbr_right(float v) {
  return __int_as_float(__builtin_amdgcn_update_dpp(
      0, __float_as_int(v), 0x130 /*WAVE_SHL1*/, 0xf, 0xf, true));
}

// LLC-coherent (cross-XCD) 8B access: agent-scope relaxed -> sc0 sc1.
__device__ __forceinline__ ull pload(const ull* p) {
  return __hip_atomic_load(p, __ATOMIC_RELAXED, __HIP_MEMORY_SCOPE_AGENT);
}
__device__ __forceinline__ void pstore(ull* p, ull v) {
  __hip_atomic_store(p, v, __ATOMIC_RELAXED, __HIP_MEMORY_SCOPE_AGENT);
}

// pack (cur, prev) into one self-tagged 8B word: low 2 bits of prev's
// mantissa carry the phase tag (<= 3 ulp perturbation of halo prev only)
__device__ __forceinline__ ull pack_w(float cur, float prev, unsigned tg) {
  const unsigned hi = (__float_as_uint(prev) & ~3u) | tg;
  return ((ull)hi << 32) | (ull)__float_as_uint(cur);
}
__device__ __forceinline__ float w_cur(ull w) {
  return __uint_as_float((unsigned)w);
}
__device__ __forceinline__ float w_prev(ull w) {
  return __uint_as_float(((unsigned)(w >> 32)) & ~3u);
}
// per-buffer tag cycles 1,2,3 (phase q uses buffer q&1): never 0 (= memset)
__device__ __forceinline__ unsigned tag_of(int q) {
  return ((unsigned)(q >> 1) % 3u) + 1u;
}

__global__ __launch_bounds__(BLOCK, 5) void wave_pk(
    ull* __restrict__ gA, ull* __restrict__ gB,         // tagged (cur,prev) buffers
    const float* __restrict__ vp, const float* __restrict__ xwav,
    const int* __restrict__ src_z, const int* __restrict__ src_x,
    const int* __restrict__ rec_z, const int* __restrict__ rec_x,
    float* __restrict__ out)                            // [NSHOTS*NT*NRECS]
{
  const int bid  = blockIdx.x;
  const int s    = bid / (NTZ * NTX);
  const int rem  = bid - s * (NTZ * NTX);
  const int tz   = rem / NTX;
  const int tx   = rem - tz * NTX;
  const int tid  = threadIdx.x;
  const int w    = tid >> 6;
  const int lane = tid & 63;

  const int gz0 = tz * TZI - KS;        // ext origin (z), 24 rows
  const int gx0 = tx * TXI - KS;        // ext origin (x), 64 lanes
  const int gx  = gx0 + lane;
  const int zb  = w * RPW;

  __shared__ float haloTop[2][NW][64];
  __shared__ float haloBot[2][NW][64];
  __shared__ int   lzA[NRECS], lxA[NRECS];

  // receiver table -> LDS (tile-local coords)
  if (tid < NRECS) {
    lzA[tid] = rec_z[s * NRECS + tid] - tz * TZI;
    lxA[tid] = rec_x[s * NRECS + tid] - tx * TXI;
  }
  __syncthreads();

  // interior (owner/writeback) threads: waves 2,3 (ext rows 8..15),
  // interior lanes 8..55
  const bool wbT = (w == 2 || w == 3) && (lane >= KS && lane < KS + TXI);

  // receiver ownership: 2 packed fast slots + overflow bitmask
  unsigned e0 = 0, e1 = 0, ov[4] = {0, 0, 0, 0};
  if (wbT) {
    int cnt = 0;
    #pragma unroll 1
    for (int r = 0; r < NRECS; ++r) {
      const int lz = lzA[r], lx = lxA[r];
      if ((unsigned)lz < (unsigned)TZI && (unsigned)lx < (unsigned)TXI) {
        if ((2 + (lz >> 2)) == w && lx + KS == lane) {
          const unsigned e = 0x8000u | ((unsigned)(lz & 3) << 8) | (unsigned)r;
          if (cnt == 0) e0 = e;
          else if (cnt == 1) e1 = e;
          else ov[r >> 5] |= 1u << (r & 31);
          ++cnt;
        }
      }
    }
  }
  const bool hasOvf = (ov[0] | ov[1] | ov[2] | ov[3]) != 0;

  // source: ext coords; wave-uniform guard (redundant injection anywhere in
  // my ext window keeps halo evolution consistent across overlapping tiles)
  const int slz = src_z[s] - gz0;
  const int slx = src_x[s] - gx0;
  const int si  = slz - zb;
  const bool hasSrcW = ((unsigned)slx < 64u) && ((unsigned)si < (unsigned)RPW);
  const bool srcMine = hasSrcW && (slx == lane);
  v2f srcM2[NPAIRS];
  #pragma unroll
  for (int p = 0; p < NPAIRS; ++p) {
    srcM2[p].x = (srcMine && si == 2 * p)     ? 1.0f : 0.0f;
    srcM2[p].y = (srcMine && si == 2 * p + 1) ? 1.0f : 0.0f;
  }

  // phase-invariant per-row addresses/validity; c2 and d2=2-4c2 packed
  const bool xok = (unsigned)gx < (unsigned)NX;
  int   offRow[RPW];
  bool  okRow[RPW];
  v2f a2[NPAIRS], b2[NPAIRS], c22[NPAIRS], d22[NPAIRS];
  unsigned okMask = 0;
  #pragma unroll
  for (int p = 0; p < NPAIRS; ++p) {
    #pragma unroll
    for (int h = 0; h < 2; ++h) {
      const int i  = 2 * p + h;
      const int gz = gz0 + zb + i;
      const bool ok = xok && ((unsigned)gz < (unsigned)NZ);
      okRow[i]  = ok;
      if (ok) okMask |= 1u << i;
      offRow[i] = ok ? ((s * NZ + gz) * NX + gx) : 0;
      float v = ok ? vp[gz * NX + gx] : 0.0f;
      v *= DTf;
      const float c2 = v * v * INVDH2;
      if (h == 0) { c22[p].x = c2; d22[p].x = 2.0f - 4.0f * c2; }
      else        { c22[p].y = c2; d22[p].y = 2.0f - 4.0f * c2; }
    }
    a2[p] = (v2f)(0.0f); b2[p] = (v2f)(0.0f);
  }

  // value of my-wave ext row (0..3) from nxt pairs
  auto selRow = [](const v2f (&n)[NPAIRS], int row) -> float {
    const v2f pp = (row & 2) ? n[1] : n[0];
    return (row & 1) ? pp.y : pp.x;
  };

  float amp[KS];

  #pragma unroll 1
  for (int ph = 0; ph < NPH; ++ph) {
    const int t0 = ph * KS;

    if (hasSrcW) {                       // wavelet only for source waves
      const float4 v  = *(const float4*)(xwav + s * NT + t0);
      const float4 u4 = *(const float4*)(xwav + s * NT + t0 + 4);
      amp[0] = v.x * DTf * DTf;  amp[1] = v.y * DTf * DTf;
      amp[2] = v.z * DTf * DTf;  amp[3] = v.w * DTf * DTf;
      amp[4] = u4.x * DTf * DTf; amp[5] = u4.y * DTf * DTf;
      amp[6] = u4.z * DTf * DTf; amp[7] = u4.w * DTf * DTf;
    }

    if (ph > 0 && !wbT) {
      // fused poll+reload on self-tagged data words (R6-proven): tag match
      // certifies the owner's phase-(ph-1) writeback AND (program order:
      // its reload loop's loads are consumed before its stores issue) its
      // prior reload of the buffer I overwrite this phase -> data-dep and
      // anti-dep both covered. Works uniformly for z/x/diagonal owners.
      const ull* gR = (ph & 1) ? gA : gB;   // buffer[(ph-1)&1]
      const unsigned tg = tag_of(ph - 1);
      ull vw[RPW];
      unsigned need = okMask;
      while (need) {
        ull t[RPW];
        #pragma unroll
        for (int i = 0; i < RPW; ++i)
          if (need & (1u << i)) t[i] = pload(gR + offRow[i]);
        #pragma unroll
        for (int i = 0; i < RPW; ++i)
          if ((need & (1u << i)) && (((unsigned)(t[i] >> 32)) & 3u) == tg) {
            vw[i] = t[i];
            need &= ~(1u << i);
          }
        if (need) __builtin_amdgcn_s_sleep(1);
      }
      #pragma unroll
      for (int i = 0; i < RPW; ++i) {
        const float cv = okRow[i] ? w_cur(vw[i])  : 0.0f;
        const float pv = okRow[i] ? w_prev(vw[i]) : 0.0f;
        if (i & 1) { a2[i >> 1].y = cv; b2[i >> 1].y = pv; }
        else       { a2[i >> 1].x = cv; b2[i >> 1].x = pv; }
      }
    }

    // one step: publish boundary rows (slot tau&1), barrier, read halos,
    // 2-pair packed stencil, optional src FMA, direct receiver stores.
    auto do_step = [&](v2f (&cur)[NPAIRS], v2f (&nxt)[NPAIRS], int tau) {
      const int pb = tau & 1;
      haloTop[pb][w][lane] = cur[0].x;
      haloBot[pb][w][lane] = cur[NPAIRS - 1].y;
      __syncthreads();
      const float up0 = (w > 0)      ? haloBot[pb][w - 1][lane] : 0.0f;
      const float dn  = (w < NW - 1) ? haloTop[pb][w + 1][lane] : 0.0f;
      #pragma unroll
      for (int p = 0; p < NPAIRS; ++p) {
        const float cx = cur[p].x, cy = cur[p].y;
        const float upx = (p == 0)          ? up0 : cur[p - 1].y;
        const float dny = (p == NPAIRS - 1) ? dn  : cur[p + 1].x;
        v2f ud, lr;
        ud.x = upx + cy;
        ud.y = cx + dny;
        lr.x = nbr_left(cx) + nbr_right(cx);
        lr.y = nbr_left(cy) + nbr_right(cy);
        const v2f sum = ud + lr;
        v2f t = __builtin_elementwise_fma(c22[p], sum, -nxt[p]);
        t = __builtin_elementwise_fma(d22[p], cur[p], t);
        nxt[p] = t;
      }
      if (hasSrcW) {                     // wave-uniform; few waves pay
        const v2f av = { amp[tau], amp[tau] };
        #pragma unroll
        for (int p = 0; p < NPAIRS; ++p)
          nxt[p] = __builtin_elementwise_fma(srcM2[p], av, nxt[p]);
      }
      // out[t0+tau] = state after this step (owner holds it in registers)
      const int t = t0 + tau;
      if (e0 & 0x8000u)
        out[(s * NT + t) * NRECS + (e0 & 127u)] = selRow(nxt, (e0 >> 8) & 3);
      if (e1 & 0x8000u)
        out[(s * NT + t) * NRECS + (e1 & 127u)] = selRow(nxt, (e1 >> 8) & 3);
      if (hasOvf) {                      // >2 recs on one thread (rare)
        #pragma unroll
        for (int wd = 0; wd < 4; ++wd) {
          unsigned m = ov[wd];
          while (m) {
            const int b = __builtin_ctz(m); m &= m - 1;
            const int r = wd * 32 + b;
            out[(s * NT + t) * NRECS + r] = selRow(nxt, lzA[r] & 3);
          }
        }
      }
    };

    #pragma unroll
    for (int h = 0; h < KS / 2; ++h) {
      do_step(a2, b2, 2 * h);
      do_step(b2, a2, 2 * h + 1);
    }
    // after 8 steps: a2 = p(t0+8), b2 = p(t0+7); exact on interior rows

    if (ph != NPH - 1 && wbT) {
      // tagged writeback IS the inter-tile handshake (no drain, no flag).
      // No end-of-phase barrier: slot-0 WAR for next phase's step 0 is
      // covered by step-7's collective barrier (R12 argument).
      ull* gW = (ph & 1) ? gB : gA;      // buffer[ph&1]
      const unsigned tgw = tag_of(ph);
      #pragma unroll
      for (int i = 0; i < RPW; ++i)
        if (okRow[i]) {                  // ragged last x-tile: skip gx>=NX
          const float cv = (i & 1) ? a2[i >> 1].y : a2[i >> 1].x;
          const float pv = (i & 1) ? b2[i >> 1].y : b2[i >> 1].x;
          pstore(gW + offRow[i], pack_w(cv, pv, tgw));
        }
    }
  }
}

extern "C" void kernel_launch(void* const* d_in, const int* in_sizes, int n_in,
                              void* d_out, int out_size, void* d_ws, size_t ws_size,
                              hipStream_t stream) {
  const float* x     = (const float*)d_in[0];
  const float* vp    = (const float*)d_in[1];
  const int*   src_z = (const int*)d_in[2];
  const int*   src_x = (const int*)d_in[3];
  const int*   rec_z = (const int*)d_in[4];
  const int*   rec_x = (const int*)d_in[5];
  float* out = (float*)d_out;

  const size_t F = (size_t)NSHOTS * NZ * NX;
  ull* gA = (ull*)d_ws;                 // tagged (cur,prev), F words
  ull* gB = gA + F;                     // F words

  // zero both buffers: tag bits 0 never match any valid tag (1..3)
  hipMemsetAsync(gA, 0, 2 * F * sizeof(ull), stream);

  wave_pk<<<dim3(NTILES), dim3(BLOCK), 0, stream>>>(
      gA, gB, vp, x, src_z, src_x, rec_z, rec_x, out);
}

// Round 14
// 317.518 us; speedup vs baseline: 1.1634x; 1.1634x over previous
//
#include <hip/hip_runtime.h>

#define NSHOTS 4
#define NT     512
#define NZ     256
#define NX     256
#define NRECS  128

static constexpr float DTf    = 0.001f;
static constexpr float INVDH2 = 1.0f / (10.0f * 10.0f);

#define KSTEPS 16                 // fused steps per phase (= halo radius)
#define TILEZ  16                 // interior tile height (z)
#define TILEX  32                 // interior tile width  (x)
#define RPT    6                  // ext rows per thread (3 v2f pairs)
#define NPAIRS 3                  // RPT/2
#define NWAVES 8
#define BLOCK  512
#define NTZ    16                 // z tiles
#define NTX    8                  // x tiles
#define NWG    (NSHOTS * NTZ * NTX)   // 512 WGs -> 2 per CU (co-resident)
#define NPHASE (NT / KSTEPS)      // 32

typedef float v2f __attribute__((ext_vector_type(2)));
typedef unsigned long long ull;

// lane i <- lane i-1 (left x-neighbor); OOB lane 0 reads 0 (bound_ctrl=1)
__device__ __forceinline__ float nbr_left(float v) {
  return __int_as_float(__builtin_amdgcn_update_dpp(
      0, __float_as_int(v), 0x138 /*WAVE_SHR1*/, 0xf, 0xf, true));
}
// lane i <- lane i+1 (right x-neighbor); OOB lane 63 reads 0
__device__ __forceinline__ float nbr_right(float v) {
  return __int_as_float(__builtin_amdgcn_update_dpp(
      0, __float_as_int(v), 0x130 /*WAVE_SHL1*/, 0xf, 0xf, true));
}

// LLC-coherent (cross-XCD) 8B access: agent-scope relaxed -> sc0 sc1.
__device__ __forceinline__ ull pload(const ull* p) {
  return __hip_atomic_load(p, __ATOMIC_RELAXED, __HIP_MEMORY_SCOPE_AGENT);
}
__device__ __forceinline__ void pstore(ull* p, ull v) {
  __hip_atomic_store(p, v, __ATOMIC_RELAXED, __HIP_MEMORY_SCOPE_AGENT);
}

// pack (cur, prev) into one self-tagged 8B word: low 2 bits of prev's
// mantissa carry the phase tag (<= 3 ulp perturbation of halo prev only)
__device__ __forceinline__ ull pack_w(float cur, float prev, unsigned tg) {
  const unsigned hi = (__float_as_uint(prev) & ~3u) | tg;
  return ((ull)hi << 32) | (ull)__float_as_uint(cur);
}
__device__ __forceinline__ float w_cur(ull w) {
  return __uint_as_float((unsigned)w);
}
__device__ __forceinline__ float w_prev(ull w) {
  return __uint_as_float(((unsigned)(w >> 32)) & ~3u);
}
// per-buffer tag cycles 1,2,3 (phase q uses buffer q&1): never 0 (= memset)
__device__ __forceinline__ unsigned tag_of(int q) {
  return ((unsigned)(q >> 1) % 3u) + 1u;
}

__global__ __launch_bounds__(BLOCK, 4) void wave_pk(
    ull* __restrict__ gA, ull* __restrict__ gB,         // tagged (cur,prev) buffers
    const float* __restrict__ vp, const float* __restrict__ xwav,
    const int* __restrict__ src_z, const int* __restrict__ src_x,
    const int* __restrict__ rec_z, const int* __restrict__ rec_x,
    float* __restrict__ out)                            // [NSHOTS*NT*NRECS]
{
  const int bid  = blockIdx.x;
  const int s    = bid >> 7;
  const int tz   = (bid >> 3) & 15;
  const int tx   = bid & 7;
  const int tid  = threadIdx.x;
  const int w    = tid >> 6;
  const int lane = tid & 63;

  const int gz0 = tz * TILEZ - KSTEPS;  // ext origin (z): 48 rows
  const int gx0 = tx * TILEX - KSTEPS;  // ext origin (x): 64 lanes
  const int gx  = gx0 + lane;
  const int zb  = w * RPT;              // my rows: zb..zb+5

  __shared__ float haloTop[2][NWAVES][64];
  __shared__ float haloBot[2][NWAVES][64];
  __shared__ float recTile[2][TILEZ][TILEX + 1];
  __shared__ int   cntS;
  __shared__ int   lzA[NRECS], lxA[NRECS];
  __shared__ unsigned pkA[NRECS];

  // ---- prologue: receiver compaction + masks (R6 scheme) ----
  if (tid == 0) cntS = 0;
  __syncthreads();
  if (tid < NRECS) {
    const int lz = rec_z[s * NRECS + tid] - tz * TILEZ;
    const int lx = rec_x[s * NRECS + tid] - tx * TILEX;
    lzA[tid] = lz; lxA[tid] = lx;
    if ((unsigned)lz < (unsigned)TILEZ && (unsigned)lx < (unsigned)TILEX) {
      const int k = atomicAdd(&cntS, 1);
      pkA[k] = (unsigned)tid | ((unsigned)lz << 8) | ((unsigned)lx << 16);
    }
  }
  __syncthreads();
  const int nRec = cntS;
  int myR = 0, myLz = 0, myLx = 0;
  if (tid < nRec) {
    const unsigned p = pkA[tid];
    myR = p & 255; myLz = (p >> 8) & 31; myLx = (p >> 16) & 31;
  }

  // per-row ownership: interior rows [16,32) straddle waves 2..5 (2+6+6+2)
  const bool wbLane = (lane >= KSTEPS && lane < KSTEPS + TILEX);
  unsigned keepM = 0;
  #pragma unroll
  for (int i = 0; i < RPT; ++i)
    if (wbLane && (unsigned)(zb + i - KSTEPS) < (unsigned)TILEZ)
      keepM |= 1u << i;

  unsigned recMask = 0;
  if (wbLane) {
    for (int r = 0; r < NRECS; ++r)
      if (lxA[r] == lane - KSTEPS && (unsigned)lzA[r] < (unsigned)TILEZ) {
        const int i = lzA[r] + KSTEPS - zb;
        if ((unsigned)i < (unsigned)RPT) recMask |= 1u << i;
      }
  }

  // source mask, packed per row-pair (uniform FMA pass, as R6)
  const int slz = src_z[s] - gz0;
  const int slx = src_x[s] - gx0;
  const bool srcMine = (slx == lane) && ((unsigned)(slz - zb) < (unsigned)RPT);
  const int  srcI = slz - zb;
  v2f srcM2[NPAIRS];
  #pragma unroll
  for (int p = 0; p < NPAIRS; ++p) {
    srcM2[p].x = (srcMine && srcI == 2 * p)     ? 1.0f : 0.0f;
    srcM2[p].y = (srcMine && srcI == 2 * p + 1) ? 1.0f : 0.0f;
  }

  // phase-invariant per-row addresses/validity; c2 and d2=2-4c2 packed
  const bool xok = (unsigned)gx < (unsigned)NX;
  int   offRow[RPT];
  bool  okRow[RPT];
  v2f a2[NPAIRS], b2[NPAIRS], c22[NPAIRS], d22[NPAIRS];
  unsigned okMask = 0;
  #pragma unroll
  for (int p = 0; p < NPAIRS; ++p) {
    #pragma unroll
    for (int h = 0; h < 2; ++h) {
      const int i  = 2 * p + h;
      const int gz = gz0 + zb + i;
      const bool ok = xok && ((unsigned)gz < (unsigned)NZ);
      okRow[i]  = ok;
      if (ok) okMask |= 1u << i;
      offRow[i] = ok ? ((s * NZ + gz) * NX + gx) : 0;
      float v = ok ? vp[gz * NX + gx] : 0.0f;
      v *= DTf;
      const float c2 = v * v * INVDH2;
      if (h == 0) { c22[p].x = c2; d22[p].x = 2.0f - 4.0f * c2; }
      else        { c22[p].y = c2; d22[p].y = 2.0f - 4.0f * c2; }
    }
    a2[p] = (v2f)(0.0f); b2[p] = (v2f)(0.0f);
  }
  const unsigned rlM = okMask & ~keepM;   // rows reloaded each phase

  #pragma unroll 1
  for (int ph = 0; ph < NPHASE; ++ph) {
    const int t0 = ph * KSTEPS;

    // 16 source amps via 4 vector loads
    float amp[KSTEPS];
    {
      const float4* xw4 = (const float4*)(xwav + s * NT + t0);
      #pragma unroll
      for (int q = 0; q < KSTEPS / 4; ++q) {
        const float4 v = xw4[q];
        amp[4 * q + 0] = (v.x * DTf) * DTf;
        amp[4 * q + 1] = (v.y * DTf) * DTf;
        amp[4 * q + 2] = (v.z * DTf) * DTf;
        amp[4 * q + 3] = (v.w * DTf) * DTf;
      }
    }

    if (ph > 0 && rlM) {
      // fused poll+reload on self-tagged data words (R6-proven): tag match
      // certifies the owner's phase-(ph-1) writeback AND (program order:
      // its reload loads are consumed before its stores issue) its prior
      // reload of the buffer I overwrite this phase -> data-dep + anti-dep
      // covered; 3-tag cycle + <=1-phase mutual-neighbor lead bound: no ABA.
      const ull* gR = (ph & 1) ? gA : gB;   // buffer[(ph-1)&1]
      const unsigned tg = tag_of(ph - 1);
      ull vw[RPT];
      unsigned need = rlM;
      while (need) {
        ull t[RPT];
        #pragma unroll
        for (int i = 0; i < RPT; ++i)
          if (need & (1u << i)) t[i] = pload(gR + offRow[i]);
        #pragma unroll
        for (int i = 0; i < RPT; ++i)
          if ((need & (1u << i)) && (((unsigned)(t[i] >> 32)) & 3u) == tg) {
            vw[i] = t[i];
            need &= ~(1u << i);
          }
        if (need) __builtin_amdgcn_s_sleep(1);
      }
      #pragma unroll
      for (int i = 0; i < RPT; ++i)
        if ((rlM >> i) & 1) {
          const float cv = w_cur(vw[i]);
          const float pv = w_prev(vw[i]);
          if (i & 1) { a2[i >> 1].y = cv; b2[i >> 1].y = pv; }
          else       { a2[i >> 1].x = cv; b2[i >> 1].x = pv; }
        }
    }

    float recv[KSTEPS];

    // one step, row-pair packed: p' = d2*c + c2*sum - prev (+ src)
    auto do_step = [&](v2f (&cur)[NPAIRS], v2f (&nxt)[NPAIRS], int tau) {
      const int pb = tau & 1;
      haloTop[pb][w][lane] = cur[0].x;
      haloBot[pb][w][lane] = cur[NPAIRS - 1].y;
      __syncthreads();
      if (tau > 0 && tid < nRec) recv[tau - 1] = recTile[1 - pb][myLz][myLx];
      const float up0 = (w > 0)          ? haloBot[pb][w - 1][lane] : 0.0f;
      const float dn7 = (w < NWAVES - 1) ? haloTop[pb][w + 1][lane] : 0.0f;
      const v2f av = { amp[tau], amp[tau] };
      #pragma unroll
      for (int p = 0; p < NPAIRS; ++p) {
        const float cx = cur[p].x, cy = cur[p].y;
        const float upx = (p == 0)          ? up0 : cur[p - 1].y;
        const float dny = (p == NPAIRS - 1) ? dn7 : cur[p + 1].x;
        v2f ud, lr;
        ud.x = upx + cy;
        ud.y = cx + dny;
        lr.x = nbr_left(cx) + nbr_right(cx);
        lr.y = nbr_left(cy) + nbr_right(cy);
        const v2f sum = ud + lr;
        v2f t = __builtin_elementwise_fma(c22[p], sum, -nxt[p]);
        t = __builtin_elementwise_fma(d22[p], cur[p], t);
        t = __builtin_elementwise_fma(srcM2[p], av, t);
        nxt[p] = t;
      }
      if (recMask) {
        #pragma unroll
        for (int i = 0; i < RPT; ++i)
          if (recMask & (1u << i))
            recTile[pb][zb + i - KSTEPS][lane - KSTEPS] =
                (i & 1) ? nxt[i >> 1].y : nxt[i >> 1].x;
      }
    };

    #pragma unroll
    for (int h = 0; h < KSTEPS / 2; ++h) {
      do_step(a2, b2, 2 * h);
      do_step(b2, a2, 2 * h + 1);
    }

    if (ph != NPHASE - 1 && keepM) {
      // tagged writeback IS the inter-tile handshake (no drain, no flag)
      ull* gW = (ph & 1) ? gB : gA;      // buffer[ph&1]
      const unsigned tgw = tag_of(ph);
      #pragma unroll
      for (int i = 0; i < RPT; ++i)
        if ((keepM >> i) & 1) {
          const float cv = (i & 1) ? a2[i >> 1].y : a2[i >> 1].x;
          const float pv = (i & 1) ? b2[i >> 1].y : b2[i >> 1].x;
          pstore(gW + offRow[i], pack_w(cv, pv, tgw));
        }
    }
    __syncthreads();                     // recTile[1] visible WG-wide

    // receiver flush (normal cached stores; read only after kernel end)
    if (tid < nRec) {
      recv[KSTEPS - 1] = recTile[1][myLz][myLx];
      #pragma unroll
      for (int t = 0; t < KSTEPS; ++t)
        out[(s * NT + (t0 + t)) * NRECS + myR] = recv[t];
    }
  }
}

extern "C" void kernel_launch(void* const* d_in, const int* in_sizes, int n_in,
                              void* d_out, int out_size, void* d_ws, size_t ws_size,
                              hipStream_t stream) {
  const float* x     = (const float*)d_in[0];
  const float* vp    = (const float*)d_in[1];
  const int*   src_z = (const int*)d_in[2];
  const int*   src_x = (const int*)d_in[3];
  const int*   rec_z = (const int*)d_in[4];
  const int*   rec_x = (const int*)d_in[5];
  float* out = (float*)d_out;

  const size_t F = (size_t)NSHOTS * NZ * NX;
  ull* gA = (ull*)d_ws;                 // tagged (cur,prev), F words
  ull* gB = gA + F;                     // F words

  // zero both buffers: tag bits 0 never match any valid tag (1..3)
  hipMemsetAsync(gA, 0, 2 * F * sizeof(ull), stream);

  wave_pk<<<dim3(NWG), dim3(BLOCK), 0, stream>>>(
      gA, gB, vp, x, src_z, src_x, rec_z, rec_x, out);
}